// Round 13
// baseline (64.225 us; speedup 1.0000x reference)
//
#include <hip/hip_runtime.h>
#include <math.h>

#define DIM 4096
#define BATCH 64

typedef __attribute__((ext_vector_type(8))) short short8;
typedef __attribute__((ext_vector_type(4))) float f32x4;
typedef __attribute__((ext_vector_type(4))) unsigned int u32x4;

__device__ __forceinline__ float4 ld4(const float* p) {
    return *reinterpret_cast<const float4*>(p);
}

// f32 -> bf16 bits, round-to-nearest-even
__device__ __forceinline__ unsigned short f2bf(float f) {
    unsigned u = __builtin_bit_cast(unsigned, f);
    u = (u + 0x7fffu + ((u >> 16) & 1u)) >> 16;
    return (unsigned short)u;
}

// pack two f32 -> one u32 of two bf16 (truncation; cheap)
__device__ __forceinline__ unsigned pack_bf2(float x, float y) {
    return (__builtin_bit_cast(unsigned, x) >> 16) |
           (__builtin_bit_cast(unsigned, y) & 0xffff0000u);
}

// K1: L2-normalize rows of input_x; emit bf16 in MFMA B-fragment order.
//   B-frag: lane l, reg j -> B[(l>>4)*8 + j][l&15]
// xb1: B for phase 1 (y = W @ xnT), K-dim = k, col = b.
// xb2: B for phase 2 (d = (NC*y) @ xn), K-dim = b, col = j.
__global__ __launch_bounds__(256) void k_norm(const float* __restrict__ x,
                                              unsigned short* __restrict__ xb1,
                                              unsigned short* __restrict__ xb2) {
    const int b = blockIdx.x;
    const int tid = threadIdx.x;
    const float* row = x + (size_t)b * DIM;

    float ss = 0.f;
    for (int k = tid * 4; k < DIM; k += 256 * 4) {
        float4 v = ld4(row + k);
        ss += v.x * v.x + v.y * v.y + v.z * v.z + v.w * v.w;
    }
#pragma unroll
    for (int m = 32; m >= 1; m >>= 1) ss += __shfl_xor(ss, m, 64);

    __shared__ float wsum[4];
    if ((tid & 63) == 0) wsum[tid >> 6] = ss;
    __syncthreads();
    const float total = wsum[0] + wsum[1] + wsum[2] + wsum[3];
    const float scale = 1.0f / (sqrtf(total) + 1e-8f);

    const int bt = b >> 4;            // xb1 b-tile
    const int li = b & 15;            // xb1 col-in-tile
    const int ks = b >> 5;            // xb2 K-step (0/1)
    const int hi = (b & 31) >> 3;     // xb2 lane-high bits
    const int jr = b & 7;             // xb2 reg index

    for (int k = tid; k < DIM; k += 256) {
        const float v = row[k] * scale;
        const unsigned short h = f2bf(v);
        const int l1 = li | (((k & 31) >> 3) << 4);
        xb1[(size_t)((((bt * 128) + (k >> 5)) * 64 + l1) << 3) + (k & 7)] = h;
        const int l2 = (k & 15) | (hi << 4);
        xb2[(size_t)(((((k >> 4) * 2) + ks) * 64 + l2) << 3) + jr] = h;
    }
}

// Fused (R4 structure, best measured): per 16-row tile of W:
//   phase 1: y[16][64] = W_rows @ xnT   (split-K over 16 waves, MFMA, LDS-reduce)
//   phase 2: out = W - lr*G + ((-alpha/B)*y) @ xn, via wave-private LDS
//            d-transpose; coalesced 512B-run epilogue.
// R12 delta vs R4: G loads and out stores are NON-TEMPORAL (no L2/L3
// allocation) so the single-use streams stop evicting W between phases.
__global__ __launch_bounds__(1024, 4) void k_fused(const float* __restrict__ W,
                                                   const float* __restrict__ G,
                                                   const unsigned short* __restrict__ xb1,
                                                   const unsigned short* __restrict__ xb2,
                                                   float* __restrict__ out) {
    // One 132 KB buffer, reused sequentially (barriers separate the lifetimes):
    //   [0, 16384)      f32 : yp  — phase-1 per-wave partial D-tiles (64 KB)
    //   [16384, 17472)  f32 : y2  — reduced y[16][68-padded]
    //   [0, 33792)      f32 : dl  — phase-2 per-wave d-transpose (16x132 each)
    __shared__ __align__(16) float lds[33792];
    float* yp = lds;
    float* y2 = lds + 16384;

    const int tid = threadIdx.x;
    const int wv = tid >> 6;      // wave 0..15
    const int l  = tid & 63;      // lane
    const int lr = l & 15;
    const int lh = l >> 4;
    const int i0 = blockIdx.x * 16;

    // ---------------- phase 1: y = W_rows @ xnT, wave wv covers K [wv*256, +256)
    f32x4 acc0 = {0.f, 0.f, 0.f, 0.f};
    f32x4 acc1 = acc0, acc2 = acc0, acc3 = acc0;
    const short8* xb1v = (const short8*)xb1;

#pragma unroll 2
    for (int s = 0; s < 8; ++s) {
        const int kbg = wv * 8 + s;
        const float* wp = W + (size_t)(i0 + lr) * DIM + kbg * 32 + lh * 8;
        const float4 wa = ld4(wp);
        const float4 wb = ld4(wp + 4);
        const int bs = kbg * 64 + l;
        const short8 b0 = xb1v[bs];
        const short8 b1 = xb1v[bs + 8192];
        const short8 b2 = xb1v[bs + 16384];
        const short8 b3 = xb1v[bs + 24576];
        u32x4 ap;
        ap[0] = pack_bf2(wa.x, wa.y);
        ap[1] = pack_bf2(wa.z, wa.w);
        ap[2] = pack_bf2(wb.x, wb.y);
        ap[3] = pack_bf2(wb.z, wb.w);
        const short8 a = __builtin_bit_cast(short8, ap);
        acc0 = __builtin_amdgcn_mfma_f32_16x16x32_bf16(a, b0, acc0, 0, 0, 0);
        acc1 = __builtin_amdgcn_mfma_f32_16x16x32_bf16(a, b1, acc1, 0, 0, 0);
        acc2 = __builtin_amdgcn_mfma_f32_16x16x32_bf16(a, b2, acc2, 0, 0, 0);
        acc3 = __builtin_amdgcn_mfma_f32_16x16x32_bf16(a, b3, acc3, 0, 0, 0);
    }
    {
        f32x4* dst = (f32x4*)yp;
        dst[(wv * 4 + 0) * 64 + l] = acc0;
        dst[(wv * 4 + 1) * 64 + l] = acc1;
        dst[(wv * 4 + 2) * 64 + l] = acc2;
        dst[(wv * 4 + 3) * 64 + l] = acc3;
    }
    __syncthreads();

    // reduce 16 partials: thread t owns y element (r = t>>6, b = t&63)
    {
        const int r  = tid >> 6;
        const int bb = tid & 63;
        const int btt = bb >> 4;
        const int lii = (bb & 15) | ((r >> 2) << 4);
        const int jq  = r & 3;
        float s = 0.f;
#pragma unroll
        for (int w = 0; w < 16; ++w) s += yp[(((w * 4 + btt) * 64 + lii) << 2) + jq];
        y2[r * 68 + bb] = s;
    }
    __syncthreads();

    // phase-2 A-fragments: ya = (-alpha/B) * y, bf16
    const float NC = -0.01f / 64.0f;
    short8 ya0, ya1;
#pragma unroll
    for (int j = 0; j < 8; ++j) {
        ya0[j] = (short)f2bf(NC * y2[lr * 68 + lh * 8 + j]);
        ya1[j] = (short)f2bf(NC * y2[lr * 68 + 32 + lh * 8 + j]);
    }
    __syncthreads();   // protect yp/y2 before dl overwrites them

    // ---------------- phase 2: wave wv owns cols [wv*256, +256), 2 chunks x 128
    constexpr float LRc = 0.001f;
    const short8* xb2v = (const short8*)xb2;
    float* dl = lds + wv * 2112;       // wave-private 16 x 132 f32
    const int c32 = (l & 31) * 4;      // col-in-chunk (float index)
    const int r0 = l >> 5;             // row parity

    for (int c = 0; c < 2; ++c) {
        // 8 jt tiles of d = ya @ xb2  (16 MFMA)
        f32x4 dt[8];
#pragma unroll
        for (int tl = 0; tl < 8; ++tl) {
            const int jt = wv * 16 + c * 8 + tl;
            const int bslot = jt * 128 + l;
            f32x4 d = {0.f, 0.f, 0.f, 0.f};
            d = __builtin_amdgcn_mfma_f32_16x16x32_bf16(ya0, xb2v[bslot], d, 0, 0, 0);
            d = __builtin_amdgcn_mfma_f32_16x16x32_bf16(ya1, xb2v[bslot + 64], d, 0, 0, 0);
            dt[tl] = d;
        }
        // transpose through wave-private LDS (write: 2-way alias = free)
#pragma unroll
        for (int tl = 0; tl < 8; ++tl)
#pragma unroll
            for (int q = 0; q < 4; ++q)
                dl[(lh * 4 + q) * 132 + tl * 16 + lr] = dt[tl][q];

        // coalesced epilogue: per instr 2 rows x 512B contiguous.
        // W: normal (cached; re-read wants L3). G: non-temporal. out: non-temporal.
        const int colg = wv * 256 + c * 128 + c32;
        float4 wv4[8];
        f32x4 gv4[8];
#pragma unroll
        for (int i = 0; i < 8; ++i) {
            const size_t gidx = (size_t)(i0 + r0 + 2 * i) * DIM + colg;
            wv4[i] = ld4(W + gidx);
            gv4[i] = __builtin_nontemporal_load(
                         reinterpret_cast<const f32x4*>(G + gidx));
        }
#pragma unroll
        for (int i = 0; i < 8; ++i) {
            const float4 dd = ld4(dl + (r0 + 2 * i) * 132 + c32);
            const size_t gidx = (size_t)(i0 + r0 + 2 * i) * DIM + colg;
            f32x4 o;
            o[0] = wv4[i].x - LRc * gv4[i][0] + dd.x;
            o[1] = wv4[i].y - LRc * gv4[i][1] + dd.y;
            o[2] = wv4[i].z - LRc * gv4[i][2] + dd.z;
            o[3] = wv4[i].w - LRc * gv4[i][3] + dd.w;
            __builtin_nontemporal_store(o, reinterpret_cast<f32x4*>(out + gidx));
        }
    }
}

extern "C" void kernel_launch(void* const* d_in, const int* in_sizes, int n_in,
                              void* d_out, int out_size, void* d_ws, size_t ws_size,
                              hipStream_t stream) {
    const float* W = (const float*)d_in[0];   // weight  (DIM x DIM)
    const float* X = (const float*)d_in[1];   // input_x (BATCH x DIM)
    const float* G = (const float*)d_in[2];   // grad    (DIM x DIM)
    float* out = (float*)d_out;

    unsigned short* xb1 = (unsigned short*)d_ws;               // 512 KB
    unsigned short* xb2 = xb1 + (size_t)DIM * BATCH;           // 512 KB

    hipLaunchKernelGGL(k_norm, dim3(BATCH), dim3(256), 0, stream, X, xb1, xb2);
    hipLaunchKernelGGL(k_fused, dim3(DIM / 16), dim3(1024), 0, stream,
                       W, G, xb1, xb2, out);
}